// Round 11
// baseline (24.559 us; speedup 1.0000x reference)
//
#include <hip/hip_runtime.h>

#define HH 14
#define WW 14
#define P 196          // HH*WW
#define CTOT 2048
#define NCHUNK 16
#define CCHUNK 128     // CTOT/NCHUNK
#define Q4 49          // P/4 float4 per channel row

// d_ws layout: [0,256) per-batch arrival counters (uint, NEVER initialized —
// mod-16 election is correct from any start incl. 0xAA poison; 2^32%16==0 so
// wraparound preserves it; proven R5/R7); [256, ...) partials (sc1 stores).

typedef unsigned long long u64;
union pk2 { float2 f; u64 u; };

__global__ __launch_bounds__(256) void fused_kernel(const float* __restrict__ fms,
                                                    unsigned* __restrict__ counters,
                                                    float* __restrict__ partials,
                                                    int* __restrict__ out) {
    const int blk = blockIdx.x;
    const int b = blk >> 4;       // batch
    const int k = blk & 15;       // channel chunk
    const float4* __restrict__ base =
        (const float4*)(fms + ((size_t)b * CTOT + (size_t)k * CCHUNK) * P);

    __shared__ float lds[5 * P];
    __shared__ float att[P];
    __shared__ float redf[4];
    __shared__ unsigned long long ball[4];
    __shared__ unsigned oldv;

    const int t = threadIdx.x;

    // ---- phase 1: stream 128 channels, partial-sum per pixel (R1 exact) ----
    if (t < 5 * Q4) {             // 245 active lanes
        const int q = t % Q4;     // float4 column within a channel row
        const int r = t / Q4;     // row-group 0..4
        float4 acc = {0.f, 0.f, 0.f, 0.f};
        #pragma unroll 4
        for (int c = r; c < CCHUNK; c += 5) {
            float4 v = base[c * Q4 + q];
            acc.x += v.x; acc.y += v.y; acc.z += v.z; acc.w += v.w;
        }
        const int o = r * P + q * 4;
        lds[o + 0] = acc.x; lds[o + 1] = acc.y;
        lds[o + 2] = acc.z; lds[o + 3] = acc.w;
    }
    __syncthreads();
    // packed-pair agent-scope write-through to LLC (98 x 8B per block; R7 protocol)
    if (t < P / 2) {
        const int p0 = 2 * t;
        pk2 v;
        v.f.x = lds[p0]     + lds[P + p0]     + lds[2 * P + p0]     + lds[3 * P + p0]     + lds[4 * P + p0];
        v.f.y = lds[p0 + 1] + lds[P + p0 + 1] + lds[2 * P + p0 + 1] + lds[3 * P + p0 + 1] + lds[4 * P + p0 + 1];
        __hip_atomic_store((u64*)(partials + (size_t)blk * P) + t, v.u,
                           __ATOMIC_RELAXED, __HIP_MEMORY_SCOPE_AGENT);
    }
    asm volatile("s_waitcnt vmcnt(0)" ::: "memory");  // this wave's stores at LLC
    __syncthreads();                                   // whole block done
    if (t == 0)
        oldv = __hip_atomic_fetch_add(&counters[b], 1u,
                                      __ATOMIC_RELAXED, __HIP_MEMORY_SCOPE_AGENT);
    __syncthreads();
    // among each batch's 16 consecutive returns exactly one is ==15 (mod 16)
    if ((oldv & 15u) != 15u) return;

    // ---- phase 2: elected block finishes batch b (cheap bitmask finisher) ----
    if (t < P / 2) {
        const u64* pb = (const u64*)(partials + (size_t)b * NCHUNK * P) + t;
        float2 acc = {0.f, 0.f};
        #pragma unroll
        for (int kk = 0; kk < NCHUNK; ++kk) {
            pk2 v;
            v.u = __hip_atomic_load(pb + kk * (P / 2), __ATOMIC_RELAXED, __HIP_MEMORY_SCOPE_AGENT);
            acc.x += v.f.x; acc.y += v.f.y;
        }
        att[2 * t] = acc.x; att[2 * t + 1] = acc.y;
    }
    __syncthreads();

    const float a = (t < P) ? att[t] : -1e30f;

    // block max: wave shuffle reduce + cross-wave LDS combine
    float mx = a;
    #pragma unroll
    for (int off = 32; off >= 1; off >>= 1) mx = fmaxf(mx, __shfl_xor(mx, off));
    if ((t & 63) == 0) redf[t >> 6] = mx;
    __syncthreads();
    const float maxv = fmaxf(fmaxf(redf[0], redf[1]), fmaxf(redf[2], redf[3]));

    const bool maskp = (t < P) && (a > maxv * 0.3f);
    const unsigned long long wb = __ballot(maskp);   // 64-bit on CDNA
    if ((t & 63) == 0) ball[t >> 6] = wb;
    __syncthreads();
    if (t >= 64) return;                             // wave 0 finishes

    const unsigned long long B0 = ball[0], B1 = ball[1], B2 = ball[2], B3 = ball[3];

    // ---- fast path: full mask == one component covering the grid ----
    if (B0 == ~0ull && B1 == ~0ull && B2 == ~0ull && (B3 & 0xFull) == 0xFull) {
        if (t == 0) {
            out[b * 4 + 0] = 0;
            out[b * 4 + 1] = 0;
            out[b * 4 + 2] = HH * 32 - 1;
            out[b * 4 + 3] = WW * 32 - 1;
        }
        return;
    }

    // ---- general path: lane-parallel flood fill (lane r owns row r) ----
    const int l = t;                                 // lane 0..63
    unsigned rem = 0;
    if (l < HH) {
        const int start = WW * l, w = start >> 6, off = start & 63;
        const unsigned long long Barr[4] = {B0, B1, B2, B3};
        unsigned long long v = Barr[w] >> off;
        if (off + WW > 64) v |= Barr[w + 1] << (64 - off);
        rem = (unsigned)v & 0x3FFFu;
    }

    unsigned bestRow = 0;
    int bestA = 0;

    // components in raster order of first pixel (= smallest label); strict '>'
    // keeps the first max -> matches argmax smallest-label tie-break
    for (;;) {
        const unsigned long long rb = __ballot(rem != 0);
        if (rb == 0) break;
        const int sr = __ffsll(rb) - 1;              // first row with a pixel
        unsigned reach = (l == sr) ? (rem & (unsigned)(-(int)rem)) : 0u;

        for (;;) {
            const unsigned h = reach | (reach << 1) | (reach >> 1);
            const unsigned up = __shfl_up(h, 1);     // lane 0: own value (harmless)
            const unsigned dn = __shfl_down(h, 1);   // lane 13: lane14 h == 0
            const unsigned nv = (h | up | dn) & rem;
            const bool chg = (nv != reach);
            reach = nv;
            if (!__any(chg)) break;
        }

        int area = __popc(reach);
        #pragma unroll
        for (int off = 32; off >= 1; off >>= 1) area += __shfl_xor(area, off);
        if (area > bestA) { bestA = area; bestRow = reach; }
        rem &= ~reach;
    }

    int mnr, mxr, mnc, mxc;
    if (bestA == 0) {                                // empty-mask fallback
        mnr = 0; mxr = HH - 1; mnc = 0; mxc = WW - 1;
    } else {
        const unsigned long long rowb = __ballot(bestRow != 0);
        mnr = __ffsll(rowb) - 1;
        mxr = 63 - __clzll(rowb);
        unsigned cols = bestRow;
        #pragma unroll
        for (int off = 32; off >= 1; off >>= 1) cols |= __shfl_xor(cols, off);
        mnc = __ffs(cols) - 1;
        mxc = 31 - __clz(cols);
    }
    if (l == 0) {
        out[b * 4 + 0] = max(mnr * 32 - 1, 0);
        out[b * 4 + 1] = max(mnc * 32 - 1, 0);
        out[b * 4 + 2] = (mxr + 1) * 32 - 1;
        out[b * 4 + 3] = (mxc + 1) * 32 - 1;
    }
}

extern "C" void kernel_launch(void* const* d_in, const int* in_sizes, int n_in,
                              void* d_out, int out_size, void* d_ws, size_t ws_size,
                              hipStream_t stream) {
    const float* fms = (const float*)d_in[0];
    int* out = (int*)d_out;
    unsigned* counters = (unsigned*)d_ws;             // 64 uints, no init needed
    float* partials = (float*)((char*)d_ws + 256);    // 1024*196 floats

    fused_kernel<<<dim3(64 * NCHUNK), dim3(256), 0, stream>>>(fms, counters, partials, out);
}

// Round 12
// 22.666 us; speedup vs baseline: 1.0835x; 1.0835x over previous
//
#include <hip/hip_runtime.h>

#define HH 14
#define WW 14
#define P 196          // HH*WW
#define CTOT 2048
#define NCHUNK 16
#define CCHUNK 128     // CTOT/NCHUNK
#define Q4 49          // P/4 float4 per channel row

// ---------------- kernel 1: partial channel sums (R1/R6 exact) ----------------
// Measured ~15.3 us (R8 double-launch diagnostic) = 102.8 MB @ 6.7 TB/s,
// ~96% of the demonstrated fabric rate (harness fills: 6.8-7.1 TB/s).
// Memory-bound at the floor — do not touch.
__global__ __launch_bounds__(256) void chansum_kernel(const float* __restrict__ fms,
                                                      float* __restrict__ partials) {
    const int blk = blockIdx.x;
    const int b = blk >> 4;       // /NCHUNK
    const int k = blk & 15;       // %NCHUNK
    const float4* __restrict__ base =
        (const float4*)(fms + ((size_t)b * CTOT + (size_t)k * CCHUNK) * P);

    __shared__ float lds[5 * P];
    const int t = threadIdx.x;

    if (t < 5 * Q4) {             // 245 active lanes
        const int q = t % Q4;     // float4 column within a channel row
        const int r = t / Q4;     // row-group 0..4
        float4 acc = {0.f, 0.f, 0.f, 0.f};
        #pragma unroll 4
        for (int c = r; c < CCHUNK; c += 5) {
            float4 v = base[c * Q4 + q];
            acc.x += v.x; acc.y += v.y; acc.z += v.z; acc.w += v.w;
        }
        const int o = r * P + q * 4;
        lds[o + 0] = acc.x; lds[o + 1] = acc.y;
        lds[o + 2] = acc.z; lds[o + 3] = acc.w;
    }
    __syncthreads();
    if (t < P) {
        float s = lds[t] + lds[P + t] + lds[2 * P + t] + lds[3 * P + t] + lds[4 * P + t];
        partials[(size_t)blk * P + t] = s;
    }
}

// ---------------- kernel 2: threshold + bitmask-CC + bbox ----------------
// grid = 64 blocks x 256 threads. Phase A: sum partials, block max, ballot.
// Then wave 0 only: all-full fast path, else lane-parallel flood fill
// (rows 0..13 one-per-lane, vertical neighbors via shfl). ~1-2 us.
__global__ __launch_bounds__(256) void bbox_kernel(const float* __restrict__ partials,
                                                   int* __restrict__ out) {
    const int b = blockIdx.x;
    const int t = threadIdx.x;

    __shared__ float redf[4];
    __shared__ unsigned long long ball[4];

    float a = -1e30f;
    if (t < P) {
        const float* pb = partials + (size_t)b * NCHUNK * P + t;
        a = 0.f;
        #pragma unroll
        for (int k = 0; k < NCHUNK; ++k) a += pb[k * P];
    }

    // block max: wave shuffle reduce + cross-wave LDS combine
    float mx = a;
    #pragma unroll
    for (int off = 32; off >= 1; off >>= 1) mx = fmaxf(mx, __shfl_xor(mx, off));
    if ((t & 63) == 0) redf[t >> 6] = mx;
    __syncthreads();
    const float maxv = fmaxf(fmaxf(redf[0], redf[1]), fmaxf(redf[2], redf[3]));

    const bool maskp = (t < P) && (a > maxv * 0.3f);
    const unsigned long long wb = __ballot(maskp);   // 64-bit on CDNA
    if ((t & 63) == 0) ball[t >> 6] = wb;
    __syncthreads();
    if (t >= 64) return;                             // wave 0 finishes

    const unsigned long long B0 = ball[0], B1 = ball[1], B2 = ball[2], B3 = ball[3];

    // ---- fast path: full mask == one component covering the grid ----
    if (B0 == ~0ull && B1 == ~0ull && B2 == ~0ull && (B3 & 0xFull) == 0xFull) {
        if (t == 0) {
            out[b * 4 + 0] = 0;
            out[b * 4 + 1] = 0;
            out[b * 4 + 2] = HH * 32 - 1;
            out[b * 4 + 3] = WW * 32 - 1;
        }
        return;
    }

    // ---- general path: lane-parallel flood fill (lane r owns row r) ----
    const int l = t;                                 // lane 0..63
    unsigned rem = 0;
    if (l < HH) {
        const int start = WW * l, w = start >> 6, off = start & 63;
        const unsigned long long Barr[4] = {B0, B1, B2, B3};
        unsigned long long v = Barr[w] >> off;
        if (off + WW > 64) v |= Barr[w + 1] << (64 - off);
        rem = (unsigned)v & 0x3FFFu;
    }

    unsigned bestRow = 0;
    int bestA = 0;

    // extract components in raster order of their first pixel (= smallest
    // label); strict '>' keeps the first max -> argmax smallest-label tie-break
    for (;;) {
        const unsigned long long rb = __ballot(rem != 0);
        if (rb == 0) break;
        const int sr = __ffsll(rb) - 1;              // first row with a pixel
        unsigned reach = (l == sr) ? (rem & (unsigned)(-(int)rem)) : 0u;

        for (;;) {
            const unsigned h = reach | (reach << 1) | (reach >> 1);
            const unsigned up = __shfl_up(h, 1);     // lane 0: own value (harmless)
            const unsigned dn = __shfl_down(h, 1);   // lane 13: lane14 h == 0
            const unsigned nv = (h | up | dn) & rem;
            const bool chg = (nv != reach);
            reach = nv;
            if (!__any(chg)) break;
        }

        int area = __popc(reach);
        #pragma unroll
        for (int off = 32; off >= 1; off >>= 1) area += __shfl_xor(area, off);
        if (area > bestA) { bestA = area; bestRow = reach; }
        rem &= ~reach;
    }

    int mnr, mxr, mnc, mxc;
    if (bestA == 0) {                                // empty-mask fallback
        mnr = 0; mxr = HH - 1; mnc = 0; mxc = WW - 1;
    } else {
        const unsigned long long rowb = __ballot(bestRow != 0);
        mnr = __ffsll(rowb) - 1;
        mxr = 63 - __clzll(rowb);
        unsigned cols = bestRow;
        #pragma unroll
        for (int off = 32; off >= 1; off >>= 1) cols |= __shfl_xor(cols, off);
        mnc = __ffs(cols) - 1;
        mxc = 31 - __clz(cols);
    }
    if (l == 0) {
        out[b * 4 + 0] = max(mnr * 32 - 1, 0);
        out[b * 4 + 1] = max(mnc * 32 - 1, 0);
        out[b * 4 + 2] = (mxr + 1) * 32 - 1;
        out[b * 4 + 3] = (mxc + 1) * 32 - 1;
    }
}

extern "C" void kernel_launch(void* const* d_in, const int* in_sizes, int n_in,
                              void* d_out, int out_size, void* d_ws, size_t ws_size,
                              hipStream_t stream) {
    const float* fms = (const float*)d_in[0];
    int* out = (int*)d_out;
    float* partials = (float*)d_ws;   // 64*NCHUNK*196 floats = 802,816 B

    chansum_kernel<<<dim3(64 * NCHUNK), dim3(256), 0, stream>>>(fms, partials);
    bbox_kernel<<<dim3(64), dim3(256), 0, stream>>>(partials, out);
}